// Round 9
// baseline (653.862 us; speedup 1.0000x reference)
//
#include <hip/hip_runtime.h>
#include <hip/hip_bf16.h>

#define N_NODES 16000
#define N_EDGES 256000

// ---- workspace layout (4-byte units) — CSR-free; total in-use 4.09 MB envelope ----
#define OFF_SIMB   512000     // float 256000  exp(sim) per edge (natural order)
#define OFF_WB     816004     // f16   36864   WZ-V weights, B-frag order (18432 dwords)
#define OFF_WBK    834436     // f16   24576   WZ-K weights, B-frag order (12288 dwords)
#define OFF_QT     846724     // f16   320000  q-tilde per node (20 f16/node; 160000 dwords)
#define OFF_Z      1006724    // float 16000   per-dst sum of exp(sim)

typedef _Float16 f16x2 __attribute__((ext_vector_type(2)));
typedef _Float16 f16x8v __attribute__((ext_vector_type(8)));
typedef float f32x4v __attribute__((ext_vector_type(4)));

__device__ __forceinline__ float fdot2f(f16x2 a, f16x2 b, float c) {
#if __has_builtin(__builtin_amdgcn_fdot2)
  return __builtin_amdgcn_fdot2(a, b, c, false);
#else
  return fmaf((float)a.x, (float)b.x, fmaf((float)a.y, (float)b.y, c));
#endif
}

__device__ __forceinline__ unsigned packh2(float a, float b) {
  union { unsigned u; f16x2 p; } v;
  v.p.x = (_Float16)a; v.p.y = (_Float16)b;
  return v.u;
}

// splat one 16-bit half of a dword across both halves (1 v_perm_b32)
__device__ __forceinline__ unsigned splat_half(unsigned x, unsigned sel) {
#if __has_builtin(__builtin_amdgcn_perm)
  return __builtin_amdgcn_perm(x, x, sel);
#else
  unsigned h = (sel == 0x03020302u) ? (x >> 16) : (x & 0xffffu);
  return h | (h << 16);
#endif
}

// async 16B global->LDS DMA (linear dest = wave-uniform base + lane*16; m97 pattern)
__device__ __forceinline__ void gload_lds16(const unsigned* g, unsigned* l) {
#if __has_builtin(__builtin_amdgcn_global_load_lds)
  __builtin_amdgcn_global_load_lds((const __attribute__((address_space(1))) unsigned*)g,
                                   (__attribute__((address_space(3))) unsigned*)l, 16, 0, 0);
#else
  *(uint4*)l = *(const uint4*)g;
#endif
}

__device__ __forceinline__ void load_row40(const float* __restrict__ p, float* xr) {
  const float4* rp = reinterpret_cast<const float4*>(p);
#pragma unroll
  for (int q = 0; q < 10; ++q) {
    float4 f = rp[q];
    xr[4 * q + 0] = f.x; xr[4 * q + 1] = f.y; xr[4 * q + 2] = f.z; xr[4 * q + 3] = f.w;
  }
}

struct EdgeGeom { float vhx, vhy, vhz, y1x, y1y, y1z; };

// geometry + radial basis + h = silu(rad @ W1n), packed as 8 f16 pairs (r11-validated)
__device__ __forceinline__ void edge_h_pk(const float* __restrict__ pos, int s, int d,
                                          const unsigned* W1, f16x2* hp, EdgeGeom& g) {
  float vx = pos[3 * d + 0] - pos[3 * s + 0];
  float vy = pos[3 * d + 1] - pos[3 * s + 1];
  float vz = pos[3 * d + 2] - pos[3 * s + 2];
  float dist = sqrtf(fmaf(vx, vx, fmaf(vy, vy, vz * vz)));
  float dsafe = fmaxf(dist, 1e-6f);
  float rinv = 1.0f / dsafe;
  g.vhx = vx * rinv; g.vhy = vy * rinv; g.vhz = vz * rinv;
  g.y1x = 1.7320508075688772f * g.vhx;
  g.y1y = 1.7320508075688772f * g.vhy;
  g.y1z = 1.7320508075688772f * g.vhz;
  float pre[16];
#pragma unroll
  for (int t = 0; t < 16; ++t) pre[t] = 0.f;
  float sx, cx;
  sincosf(1.2566370614359172f * dsafe, &sx, &cx);
  cx = fminf(1.f, fmaxf(-1.f, cx));
  float twoc = 2.f * cx;
  float sprev = 0.f, scur = sx;
  float rscale = (dist < 2.5f) ? (5.059644256269407f * rinv) : 0.f;
#pragma unroll
  for (int bp = 0; bp < 16; ++bp) {
    float r0 = rscale * scur;
    float sn = fmaf(twoc, scur, -sprev); sprev = scur; scur = sn;
    float r1 = rscale * scur;
    sn = fmaf(twoc, scur, -sprev); sprev = scur; scur = sn;
    union { unsigned u; f16x2 p; } rp; rp.p.x = (_Float16)r0; rp.p.y = (_Float16)r1;
    union { uint4 u[4]; f16x2 p[16]; } w;
    w.u[0] = *(const uint4*)(W1 + bp * 16);
    w.u[1] = *(const uint4*)(W1 + bp * 16 + 4);
    w.u[2] = *(const uint4*)(W1 + bp * 16 + 8);
    w.u[3] = *(const uint4*)(W1 + bp * 16 + 12);
#pragma unroll
    for (int t = 0; t < 16; ++t) pre[t] = fdot2f(rp.p, w.p[t], pre[t]);
  }
#pragma unroll
  for (int tp = 0; tp < 8; ++tp) {
    float h0 = pre[2 * tp]     / (1.f + __expf(-pre[2 * tp]));
    float h1 = pre[2 * tp + 1] / (1.f + __expf(-pre[2 * tp + 1]));
    hp[tp].x = (_Float16)h0; hp[tp].y = (_Float16)h1;
  }
}

// ============ fused prep: zero(Z,out) + prepB + prepBK + nodeq ============
#define PREP_ZERO_B   2563
#define PREP_PB_B     144
#define PREP_PBK_B    96
#define PREP_NQ_B     63
#define PREP_TOTAL_B  (PREP_ZERO_B + PREP_PB_B + PREP_PBK_B + PREP_NQ_B)

__global__ void __launch_bounds__(256) k_prep(
    const float* __restrict__ x,
    const float* __restrict__ Wq_s, const float* __restrict__ Wq_v,
    const float* __restrict__ Wss, const float* __restrict__ Wvv,
    const float* __restrict__ Wk2, const float* __restrict__ Wv2,
    float* __restrict__ Z, float* __restrict__ out,
    unsigned short* __restrict__ WB, unsigned short* __restrict__ WBK,
    unsigned short* __restrict__ QT) {
  int b = blockIdx.x;
  if (b < PREP_ZERO_B) {
    int i = b * 256 + threadIdx.x;          // 656128 slots, 656000 used
    if (i < 16000)       Z[i] = 0.f;
    else if (i < 656000) out[i - 16000] = 0.f;
    return;
  }
  b -= PREP_ZERO_B;
  if (b < PREP_PB_B) {
    int idx = b * 256 + threadIdx.x;        // 36864 exact
    int j = idx & 7;
    int lane = (idx >> 3) & 63;
    int t3 = idx >> 9;
    int ct = t3 % 3, kk = t3 / 3;
    int q = lane >> 4, m = lane & 15;
    int row = 32 * kk + 8 * q + j;
    int col = 16 * ct + m;
    int t = row & 15;
    float v = 0.f;
    if (row < 256) {
      int i = row >> 4;
      if (col < 16)      v = Wv2[t * 576 + i * 16 + col];
      else if (col < 24) v = Wv2[t * 576 + 384 + i * 8 + (col - 16)];
    } else if (row < 384) {
      int i = (row - 256) >> 4;
      if (col < 16)      v = Wv2[t * 576 + 256 + i * 16 + col];
    } else {
      int part = (row - 384) >> 7;
      int i = ((row - 384) & 127) >> 4;
      int cb = 24 + 8 * part;
      if (col >= cb && col < cb + 8) v = Wv2[t * 576 + 512 + i * 8 + (col - cb)];
    }
    union { unsigned short u; _Float16 h; } cv;
    cv.h = (_Float16)(v * 0.051031036307982884f);
    WB[idx] = cv.u;
    return;
  }
  b -= PREP_PB_B;
  if (b < PREP_PBK_B) {
    int idx = b * 256 + threadIdx.x;        // 24576 exact
    int j = idx & 7;
    int lane = (idx >> 3) & 63;
    int t2 = idx >> 9;
    int ct = t2 & 1, kk = t2 >> 1;
    int q = lane >> 4, m = lane & 15;
    int row = 32 * kk + 8 * q + j;
    int col = 16 * ct + m;
    int t = row & 15;
    float v = 0.f;
    if (col < 24) {
      if (row < 256) {
        int i = row >> 4;
        if (col < 8)       v = Wk2[t * 288 + i * 8 + col];
        else if (col < 12) v = Wk2[t * 288 + 192 + i * 4 + (col - 8)];
      } else if (row < 384) {
        int i = (row - 256) >> 4;
        if (col < 8)       v = Wk2[t * 288 + 128 + i * 8 + col];
      } else {
        int c = (row - 384) >> 7;
        int i = ((row - 384) & 127) >> 4;
        int cb = 12 + 4 * c;
        if (col >= cb && col < cb + 4) v = Wk2[t * 288 + 256 + i * 4 + (col - cb)];
      }
    }
    union { unsigned short u; _Float16 h; } cv;
    cv.h = (_Float16)(v * 0.051031036307982884f);
    WBK[idx] = cv.u;
    return;
  }
  b -= PREP_PBK_B;
  // ---- nodeq: per-node q-tilde, f16 store ----
  __shared__ float Ls[240];
  if (threadIdx.x < 240) {
    int i = threadIdx.x;
    float v;
    if (i < 128)      v = Wq_s[i] * 0.25f;
    else if (i < 160) v = Wq_v[i - 128] * 0.3535533905932738f;
    else if (i < 224) v = Wss[i - 160] * 0.11180339887498948f;
    else              v = Wvv[i - 224] * 0.06454972243679028f;
    Ls[i] = v;
  }
  __syncthreads();
  int n = b * 256 + threadIdx.x;
  if (n >= N_NODES) return;
  float xd[40];
  load_row40(x + 40 * n, xd);
  float qd[8], qvd[12];
#pragma unroll
  for (int o = 0; o < 8; ++o) qd[o] = 0.f;
#pragma unroll
  for (int i = 0; i < 16; ++i)
#pragma unroll
    for (int o = 0; o < 8; ++o) qd[o] = fmaf(xd[i], Ls[8 * i + o], qd[o]);
#pragma unroll
  for (int k = 0; k < 12; ++k) qvd[k] = 0.f;
#pragma unroll
  for (int i = 0; i < 8; ++i)
#pragma unroll
    for (int o = 0; o < 4; ++o)
#pragma unroll
      for (int c = 0; c < 3; ++c)
        qvd[3 * o + c] = fmaf(xd[16 + 3 * i + c], Ls[128 + 4 * i + o], qvd[3 * o + c]);
  float qf[20];
#pragma unroll
  for (int j = 0; j < 8; ++j) {
    float t = 0.f;
#pragma unroll
    for (int i = 0; i < 8; ++i) t = fmaf(qd[i], Ls[160 + 8 * i + j], t);
    qf[j] = t;
  }
#pragma unroll
  for (int o = 0; o < 4; ++o)
#pragma unroll
    for (int c = 0; c < 3; ++c) {
      float t = 0.f;
#pragma unroll
      for (int i = 0; i < 4; ++i) t = fmaf(qvd[3 * i + c], Ls[224 + 4 * i + o], t);
      qf[8 + 3 * o + c] = t;
    }
  uint2* qp = (uint2*)(QT + 20 * n);   // 40B/node, 8B-aligned
#pragma unroll
  for (int bq = 0; bq < 5; ++bq) {
    uint2 st;
    st.x = packh2(qf[4 * bq], qf[4 * bq + 1]);
    st.y = packh2(qf[4 * bq + 2], qf[4 * bq + 3]);
    qp[bq] = st;
  }
}

// ---- shared per-wave SM row (stride RSTR dwords, 16B-aligned): [0..7] HT (h, 16 f16)
//      [8..31] CF (48 coefs as 24 f16-pair dwords: dword kk = {coef 2kk, coef 2kk+1}) ----
#define RSTR 36

// build coef[48] = {xs(16), Bv(8), xv pairs per component(24)} matching WZ row order
__device__ __forceinline__ void build_coef(const float* xr, const float* Bv, float* coef) {
#pragma unroll
  for (int i = 0; i < 16; ++i) coef[i] = xr[i];
#pragma unroll
  for (int i = 0; i < 8; ++i) coef[16 + i] = Bv[i];
#pragma unroll
  for (int p = 0; p < 4; ++p)
#pragma unroll
    for (int c = 0; c < 3; ++c) {
      coef[24 + 8 * c + 2 * p]     = xr[16 + 6 * p + c];
      coef[24 + 8 * c + 2 * p + 1] = xr[16 + 6 * p + 3 + c];
    }
}

// ======= pass 1: Z-GEMM over edges in NATURAL order (no CSR); per-edge Z atomic =======
__global__ void __launch_bounds__(256) k_edge1(
    const float* __restrict__ pos, const float* __restrict__ x,
    const float* __restrict__ Wk1, const unsigned short* __restrict__ WBK,
    const unsigned short* __restrict__ QT,
    const int* __restrict__ esrc, const int* __restrict__ edst,
    float* __restrict__ simb, float* __restrict__ Z) {
  __shared__ __align__(16) unsigned LW1[256];
  __shared__ __align__(16) unsigned SM[4][64 * RSTR];
  __shared__ __align__(16) unsigned BB[2][2048];   // 2 × 8KB B-tiles

  int e = blockIdx.x * 256 + threadIdx.x;
  int s = esrc[e], d = edst[e];        // coalesced dword loads (cheaper than sd gather)

  {
    int i = threadIdx.x;
    int bp = i >> 4, t = i & 15;
    LW1[i] = packh2(Wk1[(2 * bp) * 16 + t] * 0.17677669529663687f,
                    Wk1[(2 * bp + 1) * 16 + t] * 0.17677669529663687f);
  }
  __syncthreads();

  int wave = threadIdx.x >> 6, lane = threadIdx.x & 63;
  int q = lane >> 4, m = lane & 15;
  int q1 = q & 1;
  unsigned seld = (q >> 1) ? 0x03020302u : 0x01000100u;

  f16x2 hp[8]; EdgeGeom g;
  edge_h_pk(pos, s, d, LW1, hp, g);

  // q~ load (f16, 20 halves)
  float qf[20];
  {
    const uint2* qp = (const uint2*)(QT + 20 * d);
#pragma unroll
    for (int b = 0; b < 5; ++b) {
      uint2 u = qp[b];
      union { unsigned d; f16x2 p; } a0, a1;
      a0.d = u.x; a1.d = u.y;
      qf[4 * b] = (float)a0.p.x; qf[4 * b + 1] = (float)a0.p.y;
      qf[4 * b + 2] = (float)a1.p.x; qf[4 * b + 3] = (float)a1.p.y;
    }
  }

  float xr[40];
  load_row40(x + 40 * s, xr);
  float Bv[8];
#pragma unroll
  for (int i = 0; i < 8; ++i)
    Bv[i] = fmaf(xr[16 + 3 * i], g.vhx, fmaf(xr[17 + 3 * i], g.vhy, xr[18 + 3 * i] * g.vhz));
  float coef[48];
  build_coef(xr, Bv, coef);

  unsigned* row = &SM[wave][lane * RSTR];
  {
    union { uint4 u; f16x2 p[4]; } h0, h1;
#pragma unroll
    for (int k = 0; k < 4; ++k) { h0.p[k] = hp[k]; h1.p[k] = hp[4 + k]; }
    *(uint4*)(row) = h0.u;
    *(uint4*)(row + 4) = h1.u;
  }
#pragma unroll
  for (int bt = 0; bt < 6; ++bt) {
    uint4 w;
    w.x = packh2(coef[8 * bt + 0], coef[8 * bt + 1]);
    w.y = packh2(coef[8 * bt + 2], coef[8 * bt + 3]);
    w.z = packh2(coef[8 * bt + 4], coef[8 * bt + 5]);
    w.w = packh2(coef[8 * bt + 6], coef[8 * bt + 7]);
    *(uint4*)(row + 8 + 4 * bt) = w;
  }
  unsigned* wbase = &SM[wave][0];
  union { uint4 u; f16x2 p[4]; } hs[4];
#pragma unroll
  for (int rt = 0; rt < 4; ++rt)
    hs[rt].u = *(const uint4*)(wbase + (16 * rt + m) * RSTR + 4 * q1);

  const uint4* WBq = (const uint4*)WBK;
  f32x4v acc[4][2];
#pragma unroll
  for (int rt = 0; rt < 4; ++rt)
#pragma unroll
    for (int ct = 0; ct < 2; ++ct) { f32x4v z = {0.f, 0.f, 0.f, 0.f}; acc[rt][ct] = z; }

  // prologue: stage bt=0 into buf 0 (512 uint4 per bt; 2 per thread)
#pragma unroll
  for (int j = 0; j < 2; ++j)
    gload_lds16((const unsigned*)(WBq + j * 256 + threadIdx.x),
                &BB[0][(j * 256 + threadIdx.x) * 4]);
  __syncthreads();

#pragma unroll
  for (int bt = 0; bt < 6; ++bt) {
    if (bt < 5) {
#pragma unroll
      for (int j = 0; j < 2; ++j)
        gload_lds16((const unsigned*)(WBq + (bt + 1) * 512 + j * 256 + threadIdx.x),
                    &BB[(bt + 1) & 1][(j * 256 + threadIdx.x) * 4]);
    }
    union { uint4 u; unsigned d[4]; } cb[4];
#pragma unroll
    for (int rt = 0; rt < 4; ++rt)
      cb[rt].u = *(const uint4*)(wbase + (16 * rt + m) * RSTR + 8 + 4 * bt);
    const uint4* Bq = (const uint4*)BB[bt & 1];
#pragma unroll
    for (int t = 0; t < 4; ++t) {
      union { uint4 u; f16x2 p[4]; f16x8v v; } av[4];
#pragma unroll
      for (int rt = 0; rt < 4; ++rt) {
        union { unsigned d; f16x2 p; } sp;
        sp.d = splat_half(cb[rt].d[t], seld);
#pragma unroll
        for (int w = 0; w < 4; ++w) av[rt].p[w] = hs[rt].p[w] * sp.p;
      }
#pragma unroll
      for (int ct = 0; ct < 2; ++ct) {
        union { uint4 u; f16x8v v; } bf;
        bf.u = Bq[(t * 2 + ct) * 64 + lane];
#pragma unroll
        for (int rt = 0; rt < 4; ++rt)
          acc[rt][ct] = __builtin_amdgcn_mfma_f32_16x16x32_f16(av[rt].v, bf.v, acc[rt][ct], 0, 0, 0);
      }
    }
    __syncthreads();   // drains prefetch DMA; all waves done with buf[bt&1]
  }

  // C -> P via col-major LDS (reuses wave region; per-wave in-order)
  float P[24];
  float* ctb = (float*)wbase;
#pragma unroll
  for (int rt = 0; rt < 4; ++rt)
#pragma unroll
    for (int r = 0; r < 4; ++r)
      ctb[m * 65 + 16 * rt + 4 * q + r] = acc[rt][0][r];
#pragma unroll
  for (int o = 0; o < 16; ++o) P[o] = ctb[o * 65 + lane];
#pragma unroll
  for (int rt = 0; rt < 4; ++rt)
#pragma unroll
    for (int r = 0; r < 4; ++r)
      ctb[m * 65 + 16 * rt + 4 * q + r] = acc[rt][1][r];
#pragma unroll
  for (int o = 0; o < 8; ++o) P[16 + o] = ctb[o * 65 + lane];

  float sim = 0.f;
#pragma unroll
  for (int j = 0; j < 8; ++j) sim = fmaf(qf[j], P[j], sim);
  float y1c[3] = {g.y1x, g.y1y, g.y1z};
#pragma unroll
  for (int o = 0; o < 4; ++o)
#pragma unroll
    for (int c = 0; c < 3; ++c)
      sim = fmaf(qf[8 + 3 * o + c], fmaf(y1c[c], P[8 + o], P[12 + 4 * c + o]), sim);

  // per-edge numerator + denominator (atomics are fire-and-forget; no segment machinery)
  float ev = __expf(sim);
  simb[e] = ev;                        // coalesced store
  atomicAdd(&Z[d], ev);
}

// ======= pass 2: Z-GEMM + per-edge atomic scatter (no CSR, no segment reduce) =======
__global__ void __launch_bounds__(256) k_edge2(
    const float* __restrict__ pos, const float* __restrict__ x,
    const float* __restrict__ Wv1, const unsigned short* __restrict__ WB,
    const int* __restrict__ esrc, const int* __restrict__ edst,
    const float* __restrict__ eb, const float* __restrict__ Zv,
    float* __restrict__ out) {
  __shared__ __align__(16) unsigned LW1[256];
  __shared__ __align__(16) unsigned SM[4][64 * RSTR];
  __shared__ __align__(16) unsigned BB[2][3072];   // 2 × 12KB B-tiles

  int e = blockIdx.x * 256 + threadIdx.x;
  int s = esrc[e], d = edst[e];        // coalesced

  // attention weight: exp(sim) / Z[d]  (issue both loads early)
  float ev = eb[e];                    // coalesced
  float Zd = Zv[d];                    // gather (L2/L3-resident)

  {
    int i = threadIdx.x;
    int bp = i >> 4, t = i & 15;
    LW1[i] = packh2(Wv1[(2 * bp) * 16 + t] * 0.17677669529663687f,
                    Wv1[(2 * bp + 1) * 16 + t] * 0.17677669529663687f);
  }
  __syncthreads();

  int wave = threadIdx.x >> 6, lane = threadIdx.x & 63;
  int q = lane >> 4, m = lane & 15;
  int q1 = q & 1;
  unsigned seld = (q >> 1) ? 0x03020302u : 0x01000100u;

  f16x2 hp[8]; EdgeGeom g;
  edge_h_pk(pos, s, d, LW1, hp, g);
  float xr[40];
  load_row40(x + 40 * s, xr);
  float Bv[8];
#pragma unroll
  for (int i = 0; i < 8; ++i)
    Bv[i] = fmaf(xr[16 + 3 * i], g.vhx, fmaf(xr[17 + 3 * i], g.vhy, xr[18 + 3 * i] * g.vhz));
  float coef[48];
  build_coef(xr, Bv, coef);
  float a = ev / Zd;

  unsigned* row = &SM[wave][lane * RSTR];
  {
    union { uint4 u; f16x2 p[4]; } h0, h1;
#pragma unroll
    for (int k = 0; k < 4; ++k) { h0.p[k] = hp[k]; h1.p[k] = hp[4 + k]; }
    *(uint4*)(row) = h0.u;
    *(uint4*)(row + 4) = h1.u;
  }
#pragma unroll
  for (int bt = 0; bt < 6; ++bt) {
    uint4 w;
    w.x = packh2(coef[8 * bt + 0], coef[8 * bt + 1]);
    w.y = packh2(coef[8 * bt + 2], coef[8 * bt + 3]);
    w.z = packh2(coef[8 * bt + 4], coef[8 * bt + 5]);
    w.w = packh2(coef[8 * bt + 6], coef[8 * bt + 7]);
    *(uint4*)(row + 8 + 4 * bt) = w;
  }
  unsigned* wbase = &SM[wave][0];
  union { uint4 u; f16x2 p[4]; } hs[4];
#pragma unroll
  for (int rt = 0; rt < 4; ++rt)
    hs[rt].u = *(const uint4*)(wbase + (16 * rt + m) * RSTR + 4 * q1);

  const uint4* WBq = (const uint4*)WB;
  f32x4v acc[4][3];
#pragma unroll
  for (int rt = 0; rt < 4; ++rt)
#pragma unroll
    for (int ct = 0; ct < 3; ++ct) { f32x4v z = {0.f, 0.f, 0.f, 0.f}; acc[rt][ct] = z; }

  // prologue: stage bt=0 into buf 0 (768 uint4 per bt; 3 per thread)
#pragma unroll
  for (int j = 0; j < 3; ++j)
    gload_lds16((const unsigned*)(WBq + j * 256 + threadIdx.x),
                &BB[0][(j * 256 + threadIdx.x) * 4]);
  __syncthreads();

#pragma unroll
  for (int bt = 0; bt < 6; ++bt) {
    if (bt < 5) {
#pragma unroll
      for (int j = 0; j < 3; ++j)
        gload_lds16((const unsigned*)(WBq + (bt + 1) * 768 + j * 256 + threadIdx.x),
                    &BB[(bt + 1) & 1][(j * 256 + threadIdx.x) * 4]);
    }
    union { uint4 u; unsigned d[4]; } cb[4];
#pragma unroll
    for (int rt = 0; rt < 4; ++rt)
      cb[rt].u = *(const uint4*)(wbase + (16 * rt + m) * RSTR + 8 + 4 * bt);
    const uint4* Bq = (const uint4*)BB[bt & 1];
#pragma unroll
    for (int t = 0; t < 4; ++t) {
      union { uint4 u; f16x2 p[4]; f16x8v v; } av[4];
#pragma unroll
      for (int rt = 0; rt < 4; ++rt) {
        union { unsigned d; f16x2 p; } sp;
        sp.d = splat_half(cb[rt].d[t], seld);
#pragma unroll
        for (int w = 0; w < 4; ++w) av[rt].p[w] = hs[rt].p[w] * sp.p;
      }
#pragma unroll
      for (int ct = 0; ct < 3; ++ct) {
        union { uint4 u; f16x8v v; } bf;
        bf.u = Bq[(t * 3 + ct) * 64 + lane];
#pragma unroll
        for (int rt = 0; rt < 4; ++rt)
          acc[rt][ct] = __builtin_amdgcn_mfma_f32_16x16x32_f16(av[rt].v, bf.v, acc[rt][ct], 0, 0, 0);
      }
    }
    __syncthreads();   // drains prefetch DMA; all waves done with buf[bt&1]
  }

  float* ctb = (float*)wbase;
  float* op = out + 40 * d;

  // chunk 0: out_s cols 0..15 — direct per-edge atomics (fire-and-forget)
  {
#pragma unroll
    for (int rt = 0; rt < 4; ++rt)
#pragma unroll
      for (int r = 0; r < 4; ++r)
        ctb[m * 65 + 16 * rt + 4 * q + r] = acc[rt][0][r];
    float P0[16];
#pragma unroll
    for (int o = 0; o < 16; ++o) P0[o] = ctb[o * 65 + lane];
#pragma unroll
    for (int o = 0; o < 16; ++o) atomicAdd(op + o, a * P0[o]);
  }
  // chunks 1,2
  float P1[16], P2[16];
#pragma unroll
  for (int rt = 0; rt < 4; ++rt)
#pragma unroll
    for (int r = 0; r < 4; ++r)
      ctb[m * 65 + 16 * rt + 4 * q + r] = acc[rt][1][r];
#pragma unroll
  for (int o = 0; o < 16; ++o) P1[o] = ctb[o * 65 + lane];
#pragma unroll
  for (int rt = 0; rt < 4; ++rt)
#pragma unroll
    for (int r = 0; r < 4; ++r)
      ctb[m * 65 + 16 * rt + 4 * q + r] = acc[rt][2][r];
#pragma unroll
  for (int o = 0; o < 16; ++o) P2[o] = ctb[o * 65 + lane];
#pragma unroll
  for (int o = 0; o < 8; ++o) {
    float s1v = P1[o];
    atomicAdd(op + 16 + 3 * o + 0, a * fmaf(g.y1x, s1v, P1[8 + o]));
    atomicAdd(op + 16 + 3 * o + 1, a * fmaf(g.y1y, s1v, P2[o]));
    atomicAdd(op + 16 + 3 * o + 2, a * fmaf(g.y1z, s1v, P2[8 + o]));
  }
}

extern "C" void kernel_launch(void* const* d_in, const int* in_sizes, int n_in,
                              void* d_out, int out_size, void* d_ws, size_t ws_size,
                              hipStream_t stream) {
  (void)in_sizes; (void)n_in; (void)out_size; (void)ws_size;
  const float* pos  = (const float*)d_in[0];
  const float* x    = (const float*)d_in[1];
  const float* Wq_s = (const float*)d_in[2];
  const float* Wq_v = (const float*)d_in[3];
  const float* Wk1  = (const float*)d_in[4];
  const float* Wk2  = (const float*)d_in[5];
  const float* Wv1  = (const float*)d_in[6];
  const float* Wv2  = (const float*)d_in[7];
  const float* Wss  = (const float*)d_in[8];
  const float* Wvv  = (const float*)d_in[9];
  const int* esrc = (const int*)d_in[10];
  const int* edst = (const int*)d_in[11];
  float* wsf  = (float*)d_ws;
  float* out  = (float*)d_out;

  float* simb  = wsf + OFF_SIMB;
  unsigned short* WB  = (unsigned short*)(wsf + OFF_WB);
  unsigned short* WBK = (unsigned short*)(wsf + OFF_WBK);
  unsigned short* QT  = (unsigned short*)(wsf + OFF_QT);
  float* Z    = wsf + OFF_Z;

  k_prep<<<PREP_TOTAL_B, 256, 0, stream>>>(x, Wq_s, Wq_v, Wss, Wvv, Wk2, Wv2,
                                           Z, out, WB, WBK, QT);
  k_edge1<<<1000, 256, 0, stream>>>(pos, x, Wk1, WBK, QT, esrc, edst, simb, Z);
  k_edge2<<<1000, 256, 0, stream>>>(pos, x, Wv1, WB, esrc, edst, simb, Z, out);
}

// Round 10
// 201.506 us; speedup vs baseline: 3.2449x; 3.2449x over previous
//
#include <hip/hip_runtime.h>
#include <hip/hip_bf16.h>

#define N_NODES 16000
#define N_EDGES 256000

// ---- workspace layout (4-byte units) — total 1022725*4B = 4.09 MB ----
#define OFF_SD     0          // int2  256000  (src,dst) per CSR slot, grouped by dst
#define OFF_SIMB   512000     // float 256000  exp(sim) per slot
#define OFF_CNT    768000     // int   16000   per-dst degree
#define OFF_CUR    800001     // int   16000   fill cursors
#define OFF_WB     816004     // f16   36864   WZ-V weights, B-frag order (18432 dwords)
#define OFF_WBK    834436     // f16   24576   WZ-K weights, B-frag order (12288 dwords)
#define OFF_QT     846724     // f16   320000  q-tilde per node (20 f16/node; 160000 dwords)
#define OFF_Z      1006724    // float 16000   per-dst sum of exp(sim)
#define OFF_GT     1022724    // int   1       global segment-base counter

typedef _Float16 f16x2 __attribute__((ext_vector_type(2)));
typedef _Float16 f16x8v __attribute__((ext_vector_type(8)));
typedef float f32x4v __attribute__((ext_vector_type(4)));

__device__ __forceinline__ float fdot2f(f16x2 a, f16x2 b, float c) {
#if __has_builtin(__builtin_amdgcn_fdot2)
  return __builtin_amdgcn_fdot2(a, b, c, false);
#else
  return fmaf((float)a.x, (float)b.x, fmaf((float)a.y, (float)b.y, c));
#endif
}

__device__ __forceinline__ unsigned packh2(float a, float b) {
  union { unsigned u; f16x2 p; } v;
  v.p.x = (_Float16)a; v.p.y = (_Float16)b;
  return v.u;
}

// splat one 16-bit half of a dword across both halves (1 v_perm_b32)
__device__ __forceinline__ unsigned splat_half(unsigned x, unsigned sel) {
#if __has_builtin(__builtin_amdgcn_perm)
  return __builtin_amdgcn_perm(x, x, sel);
#else
  unsigned h = (sel == 0x03020302u) ? (x >> 16) : (x & 0xffffu);
  return h | (h << 16);
#endif
}

// async 16B global->LDS DMA (linear dest = wave-uniform base + lane*16; m97 pattern)
__device__ __forceinline__ void gload_lds16(const unsigned* g, unsigned* l) {
#if __has_builtin(__builtin_amdgcn_global_load_lds)
  __builtin_amdgcn_global_load_lds((const __attribute__((address_space(1))) unsigned*)g,
                                   (__attribute__((address_space(3))) unsigned*)l, 16, 0, 0);
#else
  *(uint4*)l = *(const uint4*)g;
#endif
}

__device__ __forceinline__ void load_row40(const float* __restrict__ p, float* xr) {
  const float4* rp = reinterpret_cast<const float4*>(p);
#pragma unroll
  for (int q = 0; q < 10; ++q) {
    float4 f = rp[q];
    xr[4 * q + 0] = f.x; xr[4 * q + 1] = f.y; xr[4 * q + 2] = f.z; xr[4 * q + 3] = f.w;
  }
}

struct EdgeGeom { float vhx, vhy, vhz, y1x, y1y, y1z; };

// geometry + radial basis + h = silu(rad @ W1n), packed as 8 f16 pairs (r11-validated)
__device__ __forceinline__ void edge_h_pk(const float* __restrict__ pos, int s, int d,
                                          const unsigned* W1, f16x2* hp, EdgeGeom& g) {
  float vx = pos[3 * d + 0] - pos[3 * s + 0];
  float vy = pos[3 * d + 1] - pos[3 * s + 1];
  float vz = pos[3 * d + 2] - pos[3 * s + 2];
  float dist = sqrtf(fmaf(vx, vx, fmaf(vy, vy, vz * vz)));
  float dsafe = fmaxf(dist, 1e-6f);
  float rinv = 1.0f / dsafe;
  g.vhx = vx * rinv; g.vhy = vy * rinv; g.vhz = vz * rinv;
  g.y1x = 1.7320508075688772f * g.vhx;
  g.y1y = 1.7320508075688772f * g.vhy;
  g.y1z = 1.7320508075688772f * g.vhz;
  float pre[16];
#pragma unroll
  for (int t = 0; t < 16; ++t) pre[t] = 0.f;
  float sx, cx;
  sincosf(1.2566370614359172f * dsafe, &sx, &cx);
  cx = fminf(1.f, fmaxf(-1.f, cx));
  float twoc = 2.f * cx;
  float sprev = 0.f, scur = sx;
  float rscale = (dist < 2.5f) ? (5.059644256269407f * rinv) : 0.f;
#pragma unroll
  for (int bp = 0; bp < 16; ++bp) {
    float r0 = rscale * scur;
    float sn = fmaf(twoc, scur, -sprev); sprev = scur; scur = sn;
    float r1 = rscale * scur;
    sn = fmaf(twoc, scur, -sprev); sprev = scur; scur = sn;
    union { unsigned u; f16x2 p; } rp; rp.p.x = (_Float16)r0; rp.p.y = (_Float16)r1;
    union { uint4 u[4]; f16x2 p[16]; } w;
    w.u[0] = *(const uint4*)(W1 + bp * 16);
    w.u[1] = *(const uint4*)(W1 + bp * 16 + 4);
    w.u[2] = *(const uint4*)(W1 + bp * 16 + 8);
    w.u[3] = *(const uint4*)(W1 + bp * 16 + 12);
#pragma unroll
    for (int t = 0; t < 16; ++t) pre[t] = fdot2f(rp.p, w.p[t], pre[t]);
  }
#pragma unroll
  for (int tp = 0; tp < 8; ++tp) {
    float h0 = pre[2 * tp]     / (1.f + __expf(-pre[2 * tp]));
    float h1 = pre[2 * tp + 1] / (1.f + __expf(-pre[2 * tp + 1]));
    hp[tp].x = (_Float16)h0; hp[tp].y = (_Float16)h1;
  }
}

// ================= CSR chain (true dependencies only: hist -> scan -> fill) =========
__global__ void k_hist(const int* __restrict__ edst, int* __restrict__ cnt,
                       int* __restrict__ gtot) {
  int e = blockIdx.x * 256 + threadIdx.x;
  if (e == 0) *gtot = 0;                 // gtot consumed only after this kernel (scan2)
  atomicAdd(&cnt[edst[e]], 1);
}

// parallel segment-base assignment: order of segments is irrelevant (disjoint cover)
__global__ void k_scan2(const int* __restrict__ cnt, int* __restrict__ cur,
                        int* __restrict__ gtot) {
  int n = blockIdx.x * 256 + threadIdx.x;   // 63*256 = 16128, guard
  if (n < N_NODES) cur[n] = atomicAdd(gtot, cnt[n]);
}

// ============ k_work: fill (CSR-dependent) OVERLAPPED with all independent prep ======
// fill's contended atomics are latency-bound; zero/prepB/prepBK/nodeq blocks execute
// alongside essentially for free. Everything here completes before k_edge1 launches.
#define W_FILL_B   1000
#define W_PB_B     144
#define W_PBK_B    96
#define W_NQ_B     63
#define W_ZERO_B   2563
#define W_TOTAL_B  (W_FILL_B + W_PB_B + W_PBK_B + W_NQ_B + W_ZERO_B)

__global__ void __launch_bounds__(256) k_work(
    const int* __restrict__ esrc, const int* __restrict__ edst,
    int* __restrict__ cur, int2* __restrict__ sd,
    const float* __restrict__ x,
    const float* __restrict__ Wq_s, const float* __restrict__ Wq_v,
    const float* __restrict__ Wss, const float* __restrict__ Wvv,
    const float* __restrict__ Wk2, const float* __restrict__ Wv2,
    float* __restrict__ Z, float* __restrict__ out,
    unsigned short* __restrict__ WB, unsigned short* __restrict__ WBK,
    unsigned short* __restrict__ QT) {
  int b = blockIdx.x;
  if (b < W_FILL_B) {
    int e = b * 256 + threadIdx.x;          // 256000 exact
    int d = edst[e];
    int slot = atomicAdd(&cur[d], 1);
    sd[slot] = make_int2(esrc[e], d);
    return;
  }
  b -= W_FILL_B;
  if (b < W_PB_B) {
    int idx = b * 256 + threadIdx.x;        // 36864 exact
    int j = idx & 7;
    int lane = (idx >> 3) & 63;
    int t3 = idx >> 9;
    int ct = t3 % 3, kk = t3 / 3;
    int q = lane >> 4, m = lane & 15;
    int row = 32 * kk + 8 * q + j;
    int col = 16 * ct + m;
    int t = row & 15;
    float v = 0.f;
    if (row < 256) {
      int i = row >> 4;
      if (col < 16)      v = Wv2[t * 576 + i * 16 + col];
      else if (col < 24) v = Wv2[t * 576 + 384 + i * 8 + (col - 16)];
    } else if (row < 384) {
      int i = (row - 256) >> 4;
      if (col < 16)      v = Wv2[t * 576 + 256 + i * 16 + col];
    } else {
      int part = (row - 384) >> 7;
      int i = ((row - 384) & 127) >> 4;
      int cb = 24 + 8 * part;
      if (col >= cb && col < cb + 8) v = Wv2[t * 576 + 512 + i * 8 + (col - cb)];
    }
    union { unsigned short u; _Float16 h; } cv;
    cv.h = (_Float16)(v * 0.051031036307982884f);
    WB[idx] = cv.u;
    return;
  }
  b -= W_PB_B;
  if (b < W_PBK_B) {
    int idx = b * 256 + threadIdx.x;        // 24576 exact
    int j = idx & 7;
    int lane = (idx >> 3) & 63;
    int t2 = idx >> 9;
    int ct = t2 & 1, kk = t2 >> 1;
    int q = lane >> 4, m = lane & 15;
    int row = 32 * kk + 8 * q + j;
    int col = 16 * ct + m;
    int t = row & 15;
    float v = 0.f;
    if (col < 24) {
      if (row < 256) {
        int i = row >> 4;
        if (col < 8)       v = Wk2[t * 288 + i * 8 + col];
        else if (col < 12) v = Wk2[t * 288 + 192 + i * 4 + (col - 8)];
      } else if (row < 384) {
        int i = (row - 256) >> 4;
        if (col < 8)       v = Wk2[t * 288 + 128 + i * 8 + col];
      } else {
        int c = (row - 384) >> 7;
        int i = ((row - 384) & 127) >> 4;
        int cb = 12 + 4 * c;
        if (col >= cb && col < cb + 4) v = Wk2[t * 288 + 256 + i * 4 + (col - cb)];
      }
    }
    union { unsigned short u; _Float16 h; } cv;
    cv.h = (_Float16)(v * 0.051031036307982884f);
    WBK[idx] = cv.u;
    return;
  }
  b -= W_PBK_B;
  if (b < W_NQ_B) {
    // ---- nodeq: per-node q-tilde, f16 store ----
    __shared__ float Ls[240];
    if (threadIdx.x < 240) {
      int i = threadIdx.x;
      float v;
      if (i < 128)      v = Wq_s[i] * 0.25f;
      else if (i < 160) v = Wq_v[i - 128] * 0.3535533905932738f;
      else if (i < 224) v = Wss[i - 160] * 0.11180339887498948f;
      else              v = Wvv[i - 224] * 0.06454972243679028f;
      Ls[i] = v;
    }
    __syncthreads();
    int n = b * 256 + threadIdx.x;
    if (n >= N_NODES) return;
    float xd[40];
    load_row40(x + 40 * n, xd);
    float qd[8], qvd[12];
#pragma unroll
    for (int o = 0; o < 8; ++o) qd[o] = 0.f;
#pragma unroll
    for (int i = 0; i < 16; ++i)
#pragma unroll
      for (int o = 0; o < 8; ++o) qd[o] = fmaf(xd[i], Ls[8 * i + o], qd[o]);
#pragma unroll
    for (int k = 0; k < 12; ++k) qvd[k] = 0.f;
#pragma unroll
    for (int i = 0; i < 8; ++i)
#pragma unroll
      for (int o = 0; o < 4; ++o)
#pragma unroll
        for (int c = 0; c < 3; ++c)
          qvd[3 * o + c] = fmaf(xd[16 + 3 * i + c], Ls[128 + 4 * i + o], qvd[3 * o + c]);
    float qf[20];
#pragma unroll
    for (int j = 0; j < 8; ++j) {
      float t = 0.f;
#pragma unroll
      for (int i = 0; i < 8; ++i) t = fmaf(qd[i], Ls[160 + 8 * i + j], t);
      qf[j] = t;
    }
#pragma unroll
    for (int o = 0; o < 4; ++o)
#pragma unroll
      for (int c = 0; c < 3; ++c) {
        float t = 0.f;
#pragma unroll
        for (int i = 0; i < 4; ++i) t = fmaf(qvd[3 * i + c], Ls[224 + 4 * i + o], t);
        qf[8 + 3 * o + c] = t;
      }
    uint2* qp = (uint2*)(QT + 20 * n);   // 40B/node, 8B-aligned
#pragma unroll
    for (int bq = 0; bq < 5; ++bq) {
      uint2 st;
      st.x = packh2(qf[4 * bq], qf[4 * bq + 1]);
      st.y = packh2(qf[4 * bq + 2], qf[4 * bq + 3]);
      qp[bq] = st;
    }
    return;
  }
  b -= W_NQ_B;
  // ---- zero Z + out ----
  int i = b * 256 + threadIdx.x;            // 656128 slots, 656000 used
  if (i < 16000)       Z[i] = 0.f;
  else if (i < 656000) out[i - 16000] = 0.f;
}

// ---- shared per-wave SM row (stride RSTR dwords, 16B-aligned): [0..7] HT (h, 16 f16)
//      [8..31] CF (48 coefs as 24 f16-pair dwords: dword kk = {coef 2kk, coef 2kk+1}) ----
#define RSTR 36

// build coef[48] = {xs(16), Bv(8), xv pairs per component(24)} matching WZ row order
__device__ __forceinline__ void build_coef(const float* xr, const float* Bv, float* coef) {
#pragma unroll
  for (int i = 0; i < 16; ++i) coef[i] = xr[i];
#pragma unroll
  for (int i = 0; i < 8; ++i) coef[16 + i] = Bv[i];
#pragma unroll
  for (int p = 0; p < 4; ++p)
#pragma unroll
    for (int c = 0; c < 3; ++c) {
      coef[24 + 8 * c + 2 * p]     = xr[16 + 6 * p + c];
      coef[24 + 8 * c + 2 * p + 1] = xr[16 + 6 * p + 3 + c];
    }
}

// ======= pass 1: Z-GEMM; B staged through LDS double-buffer (8KB/bt, shared by 4 waves) =======
__global__ void __launch_bounds__(256) k_edge1(
    const float* __restrict__ pos, const float* __restrict__ x,
    const float* __restrict__ Wk1, const unsigned short* __restrict__ WBK,
    const unsigned short* __restrict__ QT,
    const int2* __restrict__ sd, float* __restrict__ simb, float* __restrict__ Z) {
  __shared__ __align__(16) unsigned LW1[256];
  __shared__ __align__(16) unsigned SM[4][64 * RSTR];
  __shared__ __align__(16) unsigned BB[2][2048];   // 2 × 8KB B-tiles

  {
    int i = threadIdx.x;
    int bp = i >> 4, t = i & 15;
    LW1[i] = packh2(Wk1[(2 * bp) * 16 + t] * 0.17677669529663687f,
                    Wk1[(2 * bp + 1) * 16 + t] * 0.17677669529663687f);
  }
  __syncthreads();

  int wave = threadIdx.x >> 6, lane = threadIdx.x & 63;
  int q = lane >> 4, m = lane & 15;
  int q1 = q & 1;
  unsigned seld = (q >> 1) ? 0x03020302u : 0x01000100u;
  int slot = blockIdx.x * 256 + threadIdx.x;
  int2 e = sd[slot];
  int s = e.x, d = e.y;

  f16x2 hp[8]; EdgeGeom g;
  edge_h_pk(pos, s, d, LW1, hp, g);

  // q~ load (f16, 20 halves)
  float qf[20];
  {
    const uint2* qp = (const uint2*)(QT + 20 * d);
#pragma unroll
    for (int b = 0; b < 5; ++b) {
      uint2 u = qp[b];
      union { unsigned d; f16x2 p; } a0, a1;
      a0.d = u.x; a1.d = u.y;
      qf[4 * b] = (float)a0.p.x; qf[4 * b + 1] = (float)a0.p.y;
      qf[4 * b + 2] = (float)a1.p.x; qf[4 * b + 3] = (float)a1.p.y;
    }
  }

  float xr[40];
  load_row40(x + 40 * s, xr);
  float Bv[8];
#pragma unroll
  for (int i = 0; i < 8; ++i)
    Bv[i] = fmaf(xr[16 + 3 * i], g.vhx, fmaf(xr[17 + 3 * i], g.vhy, xr[18 + 3 * i] * g.vhz));
  float coef[48];
  build_coef(xr, Bv, coef);

  unsigned* row = &SM[wave][lane * RSTR];
  {
    union { uint4 u; f16x2 p[4]; } h0, h1;
#pragma unroll
    for (int k = 0; k < 4; ++k) { h0.p[k] = hp[k]; h1.p[k] = hp[4 + k]; }
    *(uint4*)(row) = h0.u;
    *(uint4*)(row + 4) = h1.u;
  }
#pragma unroll
  for (int bt = 0; bt < 6; ++bt) {
    uint4 w;
    w.x = packh2(coef[8 * bt + 0], coef[8 * bt + 1]);
    w.y = packh2(coef[8 * bt + 2], coef[8 * bt + 3]);
    w.z = packh2(coef[8 * bt + 4], coef[8 * bt + 5]);
    w.w = packh2(coef[8 * bt + 6], coef[8 * bt + 7]);
    *(uint4*)(row + 8 + 4 * bt) = w;
  }
  unsigned* wbase = &SM[wave][0];
  union { uint4 u; f16x2 p[4]; } hs[4];
#pragma unroll
  for (int rt = 0; rt < 4; ++rt)
    hs[rt].u = *(const uint4*)(wbase + (16 * rt + m) * RSTR + 4 * q1);

  const uint4* WBq = (const uint4*)WBK;
  f32x4v acc[4][2];
#pragma unroll
  for (int rt = 0; rt < 4; ++rt)
#pragma unroll
    for (int ct = 0; ct < 2; ++ct) { f32x4v z = {0.f, 0.f, 0.f, 0.f}; acc[rt][ct] = z; }

  // prologue: stage bt=0 into buf 0 (512 uint4 per bt; 2 per thread)
#pragma unroll
  for (int j = 0; j < 2; ++j)
    gload_lds16((const unsigned*)(WBq + j * 256 + threadIdx.x),
                &BB[0][(j * 256 + threadIdx.x) * 4]);
  __syncthreads();

#pragma unroll
  for (int bt = 0; bt < 6; ++bt) {
    if (bt < 5) {
#pragma unroll
      for (int j = 0; j < 2; ++j)
        gload_lds16((const unsigned*)(WBq + (bt + 1) * 512 + j * 256 + threadIdx.x),
                    &BB[(bt + 1) & 1][(j * 256 + threadIdx.x) * 4]);
    }
    union { uint4 u; unsigned d[4]; } cb[4];
#pragma unroll
    for (int rt = 0; rt < 4; ++rt)
      cb[rt].u = *(const uint4*)(wbase + (16 * rt + m) * RSTR + 8 + 4 * bt);
    const uint4* Bq = (const uint4*)BB[bt & 1];
#pragma unroll
    for (int t = 0; t < 4; ++t) {
      union { uint4 u; f16x2 p[4]; f16x8v v; } av[4];
#pragma unroll
      for (int rt = 0; rt < 4; ++rt) {
        union { unsigned d; f16x2 p; } sp;
        sp.d = splat_half(cb[rt].d[t], seld);
#pragma unroll
        for (int w = 0; w < 4; ++w) av[rt].p[w] = hs[rt].p[w] * sp.p;
      }
#pragma unroll
      for (int ct = 0; ct < 2; ++ct) {
        union { uint4 u; f16x8v v; } bf;
        bf.u = Bq[(t * 2 + ct) * 64 + lane];
#pragma unroll
        for (int rt = 0; rt < 4; ++rt)
          acc[rt][ct] = __builtin_amdgcn_mfma_f32_16x16x32_f16(av[rt].v, bf.v, acc[rt][ct], 0, 0, 0);
      }
    }
    __syncthreads();   // drains prefetch DMA; all waves done with buf[bt&1]
  }

  // C -> P via col-major LDS (reuses wave region; per-wave in-order)
  float P[24];
  float* ctb = (float*)wbase;
#pragma unroll
  for (int rt = 0; rt < 4; ++rt)
#pragma unroll
    for (int r = 0; r < 4; ++r)
      ctb[m * 65 + 16 * rt + 4 * q + r] = acc[rt][0][r];
#pragma unroll
  for (int o = 0; o < 16; ++o) P[o] = ctb[o * 65 + lane];
#pragma unroll
  for (int rt = 0; rt < 4; ++rt)
#pragma unroll
    for (int r = 0; r < 4; ++r)
      ctb[m * 65 + 16 * rt + 4 * q + r] = acc[rt][1][r];
#pragma unroll
  for (int o = 0; o < 8; ++o) P[16 + o] = ctb[o * 65 + lane];

  float sim = 0.f;
#pragma unroll
  for (int j = 0; j < 8; ++j) sim = fmaf(qf[j], P[j], sim);
  float y1c[3] = {g.y1x, g.y1y, g.y1z};
#pragma unroll
  for (int o = 0; o < 4; ++o)
#pragma unroll
    for (int c = 0; c < 3; ++c)
      sim = fmaf(qf[8 + 3 * o + c], fmaf(y1c[c], P[8 + o], P[12 + 4 * c + o]), sim);

  // fused softmax numerator + per-dst denominator
  float ev = __expf(sim);
  simb[slot] = ev;
  bool same[6];
#pragma unroll
  for (int k = 0; k < 6; ++k) {
    int dd = __shfl_down(d, 1 << k, 64);
    same[k] = ((lane + (1 << k)) < 64) && (dd == d);
  }
  int dprev = __shfl_up(d, 1, 64);
  bool head = (lane == 0) || (dprev != d);
  float v = ev;
#pragma unroll
  for (int k = 0; k < 6; ++k) {
    float ov = __shfl_down(v, 1 << k, 64);
    v += same[k] ? ov : 0.f;
  }
  if (head) atomicAdd(&Z[d], v);
}

// ======= pass 2: Z-GEMM + scatter; B staged through LDS double-buffer (12KB/bt) =======
__global__ void __launch_bounds__(256) k_edge2(
    const float* __restrict__ pos, const float* __restrict__ x,
    const float* __restrict__ Wv1, const unsigned short* __restrict__ WB,
    const int2* __restrict__ sd, const float* __restrict__ eb,
    const float* __restrict__ Zv, float* __restrict__ out) {
  __shared__ __align__(16) unsigned LW1[256];
  __shared__ __align__(16) unsigned SM[4][64 * RSTR];
  __shared__ __align__(16) unsigned BB[2][3072];   // 2 × 12KB B-tiles

  {
    int i = threadIdx.x;
    int bp = i >> 4, t = i & 15;
    LW1[i] = packh2(Wv1[(2 * bp) * 16 + t] * 0.17677669529663687f,
                    Wv1[(2 * bp + 1) * 16 + t] * 0.17677669529663687f);
  }
  __syncthreads();

  int wave = threadIdx.x >> 6, lane = threadIdx.x & 63;
  int q = lane >> 4, m = lane & 15;
  int q1 = q & 1;
  unsigned seld = (q >> 1) ? 0x03020302u : 0x01000100u;
  int slot = blockIdx.x * 256 + threadIdx.x;
  int2 e = sd[slot];
  int s = e.x, d = e.y;

  // attention weight: exp(sim) / Z[d]  (issue both loads early)
  float ev = eb[slot];
  float Zd = Zv[d];

  bool same[6];
#pragma unroll
  for (int k = 0; k < 6; ++k) {
    int dd = __shfl_down(d, 1 << k, 64);
    same[k] = ((lane + (1 << k)) < 64) && (dd == d);
  }
  int dprev = __shfl_up(d, 1, 64);
  bool head = (lane == 0) || (dprev != d);

  f16x2 hp[8]; EdgeGeom g;
  edge_h_pk(pos, s, d, LW1, hp, g);
  float xr[40];
  load_row40(x + 40 * s, xr);
  float Bv[8];
#pragma unroll
  for (int i = 0; i < 8; ++i)
    Bv[i] = fmaf(xr[16 + 3 * i], g.vhx, fmaf(xr[17 + 3 * i], g.vhy, xr[18 + 3 * i] * g.vhz));
  float coef[48];
  build_coef(xr, Bv, coef);
  float a = ev / Zd;

  unsigned* row = &SM[wave][lane * RSTR];
  {
    union { uint4 u; f16x2 p[4]; } h0, h1;
#pragma unroll
    for (int k = 0; k < 4; ++k) { h0.p[k] = hp[k]; h1.p[k] = hp[4 + k]; }
    *(uint4*)(row) = h0.u;
    *(uint4*)(row + 4) = h1.u;
  }
#pragma unroll
  for (int bt = 0; bt < 6; ++bt) {
    uint4 w;
    w.x = packh2(coef[8 * bt + 0], coef[8 * bt + 1]);
    w.y = packh2(coef[8 * bt + 2], coef[8 * bt + 3]);
    w.z = packh2(coef[8 * bt + 4], coef[8 * bt + 5]);
    w.w = packh2(coef[8 * bt + 6], coef[8 * bt + 7]);
    *(uint4*)(row + 8 + 4 * bt) = w;
  }
  unsigned* wbase = &SM[wave][0];
  union { uint4 u; f16x2 p[4]; } hs[4];
#pragma unroll
  for (int rt = 0; rt < 4; ++rt)
    hs[rt].u = *(const uint4*)(wbase + (16 * rt + m) * RSTR + 4 * q1);

  const uint4* WBq = (const uint4*)WB;
  f32x4v acc[4][3];
#pragma unroll
  for (int rt = 0; rt < 4; ++rt)
#pragma unroll
    for (int ct = 0; ct < 3; ++ct) { f32x4v z = {0.f, 0.f, 0.f, 0.f}; acc[rt][ct] = z; }

  // prologue: stage bt=0 into buf 0 (768 uint4 per bt; 3 per thread)
#pragma unroll
  for (int j = 0; j < 3; ++j)
    gload_lds16((const unsigned*)(WBq + j * 256 + threadIdx.x),
                &BB[0][(j * 256 + threadIdx.x) * 4]);
  __syncthreads();

#pragma unroll
  for (int bt = 0; bt < 6; ++bt) {
    if (bt < 5) {
#pragma unroll
      for (int j = 0; j < 3; ++j)
        gload_lds16((const unsigned*)(WBq + (bt + 1) * 768 + j * 256 + threadIdx.x),
                    &BB[(bt + 1) & 1][(j * 256 + threadIdx.x) * 4]);
    }
    union { uint4 u; unsigned d[4]; } cb[4];
#pragma unroll
    for (int rt = 0; rt < 4; ++rt)
      cb[rt].u = *(const uint4*)(wbase + (16 * rt + m) * RSTR + 8 + 4 * bt);
    const uint4* Bq = (const uint4*)BB[bt & 1];
#pragma unroll
    for (int t = 0; t < 4; ++t) {
      union { uint4 u; f16x2 p[4]; f16x8v v; } av[4];
#pragma unroll
      for (int rt = 0; rt < 4; ++rt) {
        union { unsigned d; f16x2 p; } sp;
        sp.d = splat_half(cb[rt].d[t], seld);
#pragma unroll
        for (int w = 0; w < 4; ++w) av[rt].p[w] = hs[rt].p[w] * sp.p;
      }
#pragma unroll
      for (int ct = 0; ct < 3; ++ct) {
        union { uint4 u; f16x8v v; } bf;
        bf.u = Bq[(t * 3 + ct) * 64 + lane];
#pragma unroll
        for (int rt = 0; rt < 4; ++rt)
          acc[rt][ct] = __builtin_amdgcn_mfma_f32_16x16x32_f16(av[rt].v, bf.v, acc[rt][ct], 0, 0, 0);
      }
    }
    __syncthreads();   // drains prefetch DMA; all waves done with buf[bt&1]
  }

  float* ctb = (float*)wbase;
  float* op = out + 40 * d;

  // chunk 0: out_s cols 0..15
  {
#pragma unroll
    for (int rt = 0; rt < 4; ++rt)
#pragma unroll
      for (int r = 0; r < 4; ++r)
        ctb[m * 65 + 16 * rt + 4 * q + r] = acc[rt][0][r];
    float P0[16];
#pragma unroll
    for (int o = 0; o < 16; ++o) P0[o] = ctb[o * 65 + lane];
#pragma unroll
    for (int o = 0; o < 16; ++o) {
      float v = a * P0[o];
#pragma unroll
      for (int k = 0; k < 6; ++k) {
        float ov = __shfl_down(v, 1 << k, 64);
        v += same[k] ? ov : 0.f;
      }
      if (head) atomicAdd(op + o, v);
    }
  }
  // chunks 1,2
  float P1[16], P2[16];
#pragma unroll
  for (int rt = 0; rt < 4; ++rt)
#pragma unroll
    for (int r = 0; r < 4; ++r)
      ctb[m * 65 + 16 * rt + 4 * q + r] = acc[rt][1][r];
#pragma unroll
  for (int o = 0; o < 16; ++o) P1[o] = ctb[o * 65 + lane];
#pragma unroll
  for (int rt = 0; rt < 4; ++rt)
#pragma unroll
    for (int r = 0; r < 4; ++r)
      ctb[m * 65 + 16 * rt + 4 * q + r] = acc[rt][2][r];
#pragma unroll
  for (int o = 0; o < 16; ++o) P2[o] = ctb[o * 65 + lane];
#pragma unroll
  for (int o = 0; o < 8; ++o) {
    float s1v = P1[o];
    float vc[3];
    vc[0] = a * fmaf(g.y1x, s1v, P1[8 + o]);
    vc[1] = a * fmaf(g.y1y, s1v, P2[o]);
    vc[2] = a * fmaf(g.y1z, s1v, P2[8 + o]);
#pragma unroll
    for (int c = 0; c < 3; ++c) {
      float v = vc[c];
#pragma unroll
      for (int k = 0; k < 6; ++k) {
        float ov = __shfl_down(v, 1 << k, 64);
        v += same[k] ? ov : 0.f;
      }
      if (head) atomicAdd(op + 16 + 3 * o + c, v);
    }
  }
}

extern "C" void kernel_launch(void* const* d_in, const int* in_sizes, int n_in,
                              void* d_out, int out_size, void* d_ws, size_t ws_size,
                              hipStream_t stream) {
  (void)in_sizes; (void)n_in; (void)out_size; (void)ws_size;
  const float* pos  = (const float*)d_in[0];
  const float* x    = (const float*)d_in[1];
  const float* Wq_s = (const float*)d_in[2];
  const float* Wq_v = (const float*)d_in[3];
  const float* Wk1  = (const float*)d_in[4];
  const float* Wk2  = (const float*)d_in[5];
  const float* Wv1  = (const float*)d_in[6];
  const float* Wv2  = (const float*)d_in[7];
  const float* Wss  = (const float*)d_in[8];
  const float* Wvv  = (const float*)d_in[9];
  const int* esrc = (const int*)d_in[10];
  const int* edst = (const int*)d_in[11];
  int*   wsi  = (int*)d_ws;
  float* wsf  = (float*)d_ws;
  float* out  = (float*)d_out;

  int2*  sd    = (int2*)(wsi + OFF_SD);
  float* simb  = wsf + OFF_SIMB;
  int*   cnt   = wsi + OFF_CNT;
  int*   cur   = wsi + OFF_CUR;
  unsigned short* WB  = (unsigned short*)(wsf + OFF_WB);
  unsigned short* WBK = (unsigned short*)(wsf + OFF_WBK);
  unsigned short* QT  = (unsigned short*)(wsf + OFF_QT);
  float* Z    = wsf + OFF_Z;
  int*   gtot = wsi + OFF_GT;

  hipMemsetAsync(cnt, 0, (size_t)N_NODES * sizeof(int), stream);
  k_hist<<<1000, 256, 0, stream>>>(edst, cnt, gtot);
  k_scan2<<<63, 256, 0, stream>>>(cnt, cur, gtot);
  k_work<<<W_TOTAL_B, 256, 0, stream>>>(esrc, edst, cur, sd,
                                        x, Wq_s, Wq_v, Wss, Wvv, Wk2, Wv2,
                                        Z, out, WB, WBK, QT);
  k_edge1<<<1000, 256, 0, stream>>>(pos, x, Wk1, WBK, QT, sd, simb, Z);
  k_edge2<<<1000, 256, 0, stream>>>(pos, x, Wv1, WB, sd, simb, Z, out);
}